// Round 1
// baseline (2999.780 us; speedup 1.0000x reference)
//
#include <hip/hip_runtime.h>

#define TPB 256

// ---------------------------------------------------------------------------
// Kernel 1: fused edge-MLP -> node-MLP -> scatter-mean-accumulate (atomics).
// One thread per edge. Weights are wave-uniform -> scalar loads (s_load) +
// v_fmac with SGPR operand; activations live in VGPRs.
// node_acc layout: [N][16] = {15 feature sums, count}
// ---------------------------------------------------------------------------
__global__ __launch_bounds__(TPB) void edge_node_kernel(
    const float* __restrict__ x, const int* __restrict__ ei,
    const float* __restrict__ ea,
    const float* __restrict__ ew1, const float* __restrict__ eb1,
    const float* __restrict__ ew2, const float* __restrict__ eb2,
    const float* __restrict__ nw1, const float* __restrict__ nb1,
    const float* __restrict__ nw2, const float* __restrict__ nb2,
    float* __restrict__ node_acc, int E)
{
    int e = blockIdx.x * TPB + threadIdx.x;
    if (e >= E) return;
    int r = ei[e];
    int c = ei[E + e];

    float xc0 = x[3*c+0], xc1 = x[3*c+1], xc2 = x[3*c+2];
    float in9[9];
    in9[0] = x[3*r+0]; in9[1] = x[3*r+1]; in9[2] = x[3*r+2];
    in9[3] = xc0;      in9[4] = xc1;      in9[5] = xc2;
    in9[6] = ea[3*e+0]; in9[7] = ea[3*e+1]; in9[8] = ea[3*e+2];

    // edge MLP layer 1: 9 -> 50, ReLU
    float h[50];
#pragma unroll
    for (int j = 0; j < 50; ++j) h[j] = eb1[j];
#pragma unroll
    for (int i = 0; i < 9; ++i) {
        float v = in9[i];
#pragma unroll
        for (int j = 0; j < 50; ++j) h[j] = fmaf(v, ew1[i*50+j], h[j]);
    }
#pragma unroll
    for (int j = 0; j < 50; ++j) h[j] = fmaxf(h[j], 0.f);

    // edge MLP layer 2: 50 -> 15
    float e2[15];
#pragma unroll
    for (int j = 0; j < 15; ++j) e2[j] = eb2[j];
#pragma unroll
    for (int i = 0; i < 50; ++i) {
        float v = h[i];
#pragma unroll
        for (int j = 0; j < 15; ++j) e2[j] = fmaf(v, ew2[i*15+j], e2[j]);
    }

    // node MLP layer 1: [x[col](3), edge2(15)] -> 50, ReLU
    float h2[50];
#pragma unroll
    for (int j = 0; j < 50; ++j)
        h2[j] = fmaf(xc0, nw1[j], fmaf(xc1, nw1[50+j], fmaf(xc2, nw1[100+j], nb1[j])));
#pragma unroll
    for (int i = 0; i < 15; ++i) {
        float v = e2[i];
#pragma unroll
        for (int j = 0; j < 50; ++j) h2[j] = fmaf(v, nw1[(3+i)*50+j], h2[j]);
    }
#pragma unroll
    for (int j = 0; j < 50; ++j) h2[j] = fmaxf(h2[j], 0.f);

    // node MLP layer 2: 50 -> 15, scatter-add by row
    float* dst = node_acc + (size_t)r * 16;
#pragma unroll
    for (int j = 0; j < 15; ++j) {
        float acc = nb2[j];
#pragma unroll
        for (int i = 0; i < 50; ++i) acc = fmaf(h2[i], nw2[i*15+j], acc);
        atomicAdd(dst + j, acc);
    }
    atomicAdd(dst + 15, 1.0f);
}

// ---------------------------------------------------------------------------
// Kernel 2: finalize per-node mean (x2), accumulate per-graph sums + counts.
// g_acc layout: [G][16] = {15 feature sums, count}
// ---------------------------------------------------------------------------
__global__ __launch_bounds__(TPB) void node_to_global_kernel(
    const float* __restrict__ node_acc, const int* __restrict__ batch,
    float* __restrict__ g_acc, int N)
{
    int n = blockIdx.x * TPB + threadIdx.x;
    if (n >= N) return;
    const float* src = node_acc + (size_t)n * 16;
    float inv = 1.f / fmaxf(src[15], 1.f);
    int g = batch[n];
    float* dst = g_acc + (size_t)g * 16;
#pragma unroll
    for (int j = 0; j < 15; ++j) atomicAdd(dst + j, src[j] * inv);
    atomicAdd(dst + 15, 1.f);
}

// ---------------------------------------------------------------------------
// Kernel 3: global MLP + head (fc1 -> BN(batch stats) -> ReLU -> fc2 ->
// log_softmax), single block so BN stats need no grid sync. z in LDS (40KB).
// ---------------------------------------------------------------------------
__global__ __launch_bounds__(256) void global_head_kernel(
    const float* __restrict__ g_acc, const float* __restrict__ u,
    const float* __restrict__ gw1, const float* __restrict__ gb1,
    const float* __restrict__ gw2, const float* __restrict__ gb2,
    const float* __restrict__ f1w, const float* __restrict__ f1b,
    const float* __restrict__ bng, const float* __restrict__ bnb,
    const float* __restrict__ f2w, const float* __restrict__ f2b,
    float* __restrict__ out, int G)
{
    __shared__ float z[1024 * 10];   // 40 KB, G <= 1024
    __shared__ float red[2][10];

    float psum[10], psq[10];
#pragma unroll
    for (int j = 0; j < 10; ++j) { psum[j] = 0.f; psq[j] = 0.f; }

    for (int g = threadIdx.x; g < G; g += 256) {
        float gin[16];
        gin[0] = u[g];
        const float* src = g_acc + (size_t)g * 16;
        float inv = 1.f / fmaxf(src[15], 1.f);
#pragma unroll
        for (int j = 0; j < 15; ++j) gin[1 + j] = src[j] * inv;

        // global MLP: 16 -> 50 ReLU -> 15
        float h[50];
#pragma unroll
        for (int j = 0; j < 50; ++j) h[j] = gb1[j];
#pragma unroll
        for (int i = 0; i < 16; ++i) {
            float v = gin[i];
#pragma unroll
            for (int j = 0; j < 50; ++j) h[j] = fmaf(v, gw1[i*50+j], h[j]);
        }
#pragma unroll
        for (int j = 0; j < 50; ++j) h[j] = fmaxf(h[j], 0.f);

        float u2[15];
#pragma unroll
        for (int j = 0; j < 15; ++j) u2[j] = gb2[j];
#pragma unroll
        for (int i = 0; i < 50; ++i) {
            float v = h[i];
#pragma unroll
            for (int j = 0; j < 15; ++j) u2[j] = fmaf(v, gw2[i*15+j], u2[j]);
        }

        // fc1: 15 -> 10
#pragma unroll
        for (int j = 0; j < 10; ++j) {
            float acc = f1b[j];
#pragma unroll
            for (int i = 0; i < 15; ++i) acc = fmaf(u2[i], f1w[i*10+j], acc);
            z[g*10 + j] = acc;
            psum[j] += acc;
            psq[j]  += acc * acc;
        }
    }

    if (threadIdx.x == 0) {
#pragma unroll
        for (int j = 0; j < 10; ++j) { red[0][j] = 0.f; red[1][j] = 0.f; }
    }
    __syncthreads();
#pragma unroll
    for (int j = 0; j < 10; ++j) {
        atomicAdd(&red[0][j], psum[j]);
        atomicAdd(&red[1][j], psq[j]);
    }
    __syncthreads();

    float mean[10], rstd[10];
    float invG = 1.f / (float)G;
#pragma unroll
    for (int j = 0; j < 10; ++j) {
        mean[j] = red[0][j] * invG;
        float var = red[1][j] * invG - mean[j] * mean[j];
        rstd[j] = rsqrtf(var + 1e-5f);
    }

    for (int g = threadIdx.x; g < G; g += 256) {
        float l[6];
#pragma unroll
        for (int k = 0; k < 6; ++k) l[k] = f2b[k];
#pragma unroll
        for (int j = 0; j < 10; ++j) {
            float zn = (z[g*10 + j] - mean[j]) * rstd[j] * bng[j] + bnb[j];
            zn = fmaxf(zn, 0.f);
#pragma unroll
            for (int k = 0; k < 6; ++k) l[k] = fmaf(zn, f2w[j*6+k], l[k]);
        }
        float m = l[0];
#pragma unroll
        for (int k = 1; k < 6; ++k) m = fmaxf(m, l[k]);
        float s = 0.f;
#pragma unroll
        for (int k = 0; k < 6; ++k) s += expf(l[k] - m);
        float lse = m + logf(s);
#pragma unroll
        for (int k = 0; k < 6; ++k) out[g*6 + k] = l[k] - lse;
    }
}

extern "C" void kernel_launch(void* const* d_in, const int* in_sizes, int n_in,
                              void* d_out, int out_size, void* d_ws, size_t ws_size,
                              hipStream_t stream)
{
    const float* x   = (const float*)d_in[0];
    const int*   ei  = (const int*)d_in[1];
    const float* ea  = (const float*)d_in[2];
    const float* u   = (const float*)d_in[3];
    const int* batch = (const int*)d_in[4];
    const float* ew1 = (const float*)d_in[5];
    const float* eb1 = (const float*)d_in[6];
    const float* ew2 = (const float*)d_in[7];
    const float* eb2 = (const float*)d_in[8];
    const float* nw1 = (const float*)d_in[9];
    const float* nb1 = (const float*)d_in[10];
    const float* nw2 = (const float*)d_in[11];
    const float* nb2 = (const float*)d_in[12];
    const float* gw1 = (const float*)d_in[13];
    const float* gb1 = (const float*)d_in[14];
    const float* gw2 = (const float*)d_in[15];
    const float* gb2 = (const float*)d_in[16];
    const float* f1w = (const float*)d_in[17];
    const float* f1b = (const float*)d_in[18];
    const float* bng = (const float*)d_in[19];
    const float* bnb = (const float*)d_in[20];
    const float* f2w = (const float*)d_in[21];
    const float* f2b = (const float*)d_in[22];

    int N = in_sizes[0] / 3;
    int E = in_sizes[1] / 2;
    int G = in_sizes[3];

    float* node_acc = (float*)d_ws;                 // N*16 floats
    float* g_acc    = node_acc + (size_t)N * 16;    // G*16 floats

    // d_ws is poisoned 0xAA before every launch -> zero the accumulators.
    hipMemsetAsync(d_ws, 0, sizeof(float) * ((size_t)N * 16 + (size_t)G * 16),
                   stream);

    edge_node_kernel<<<(E + TPB - 1) / TPB, TPB, 0, stream>>>(
        x, ei, ea, ew1, eb1, ew2, eb2, nw1, nb1, nw2, nb2, node_acc, E);

    node_to_global_kernel<<<(N + TPB - 1) / TPB, TPB, 0, stream>>>(
        node_acc, batch, g_acc, N);

    global_head_kernel<<<1, 256, 0, stream>>>(
        g_acc, u, gw1, gb1, gw2, gb2, f1w, f1b, bng, bnb, f2w, f2b,
        (float*)d_out, G);
}

// Round 2
// 1940.928 us; speedup vs baseline: 1.5455x; 1.5455x over previous
//
#include <hip/hip_runtime.h>

#define TPB 256
#define GRP 8   // lanes per node in node_kernel

// ---------------------------------------------------------------------------
// Counting sort of edges by row: hist -> scan -> scatter(perm)
// ---------------------------------------------------------------------------
__global__ __launch_bounds__(TPB) void hist_kernel(
    const int* __restrict__ ei, unsigned* __restrict__ cnt, int E)
{
    int e = blockIdx.x * TPB + threadIdx.x;
    if (e < E) atomicAdd(&cnt[ei[e]], 1u);
}

__global__ __launch_bounds__(1024) void scan_kernel(
    const unsigned* __restrict__ cnt, unsigned* __restrict__ off,
    unsigned* __restrict__ cur, int N, int E)
{
    __shared__ unsigned part[1024];
    int t = threadIdx.x;
    int C = (N + 1023) / 1024;
    int lo = t * C, hi = min(N, lo + C);
    unsigned s = 0;
    for (int i = lo; i < hi; ++i) s += cnt[i];
    part[t] = s;
    __syncthreads();
    // Hillis-Steele inclusive scan (read-before-write each step)
    for (int st = 1; st < 1024; st <<= 1) {
        unsigned v = (t >= st) ? part[t - st] : 0u;
        __syncthreads();
        part[t] += v;
        __syncthreads();
    }
    unsigned base = part[t] - s;   // exclusive prefix of this chunk
    for (int i = lo; i < hi; ++i) {
        off[i] = base; cur[i] = base;
        base += cnt[i];
    }
    if (t == 0) off[N] = (unsigned)E;
}

__global__ __launch_bounds__(TPB) void scatter_kernel(
    const int* __restrict__ ei, unsigned* __restrict__ cur,
    unsigned* __restrict__ perm, int E)
{
    int e = blockIdx.x * TPB + threadIdx.x;
    if (e < E) {
        unsigned p = atomicAdd(&cur[ei[e]], 1u);
        perm[p] = (unsigned)e;
    }
}

// ---------------------------------------------------------------------------
// Node-centric fused kernel: GRP lanes cooperate on one node's edge list.
// Per edge: edge-MLP (9->50 relu ->15) then node-MLP layer1 (18->50), relu,
// accumulated into hacc[50]. Node-MLP layer2 (50->15) is linear => applied
// ONCE per node after reduction: sum_msg = hacc @ nw2 + deg*nb2.
// x2 = sum_msg/deg is atomically accumulated into per-graph sums g_acc.
// g_acc layout: [G][16] = {15 feature sums, node count}
// ---------------------------------------------------------------------------
__global__ __launch_bounds__(TPB) void node_kernel(
    const float* __restrict__ x, const int* __restrict__ ei,
    const float* __restrict__ ea,
    const unsigned* __restrict__ off, const unsigned* __restrict__ perm,
    const int* __restrict__ batch,
    const float* __restrict__ ew1, const float* __restrict__ eb1,
    const float* __restrict__ ew2, const float* __restrict__ eb2,
    const float* __restrict__ nw1, const float* __restrict__ nb1,
    const float* __restrict__ nw2, const float* __restrict__ nb2,
    float* __restrict__ g_acc, int N, int E)
{
    int n = blockIdx.x * (TPB / GRP) + (threadIdx.x >> 3);
    if (n >= N) return;                    // whole 8-lane group exits together
    int lane = threadIdx.x & (GRP - 1);

    unsigned s0 = off[n], s1 = off[n + 1];
    float xr0 = x[3*n+0], xr1 = x[3*n+1], xr2 = x[3*n+2];  // row == n (sorted)

    float hacc[50];
#pragma unroll
    for (int j = 0; j < 50; ++j) hacc[j] = 0.f;

    for (unsigned i = s0 + lane; i < s1; i += GRP) {
        int e = (int)perm[i];
        int c = ei[E + e];
        float xc0 = x[3*c+0], xc1 = x[3*c+1], xc2 = x[3*c+2];
        float a0 = ea[3*e+0], a1 = ea[3*e+1], a2 = ea[3*e+2];

        // edge MLP layer 1: 9 -> 50, ReLU folded into layer 2 read
        float h[50];
#pragma unroll
        for (int j = 0; j < 50; ++j) {
            float t = eb1[j];
            t = fmaf(xr0, ew1[0*50+j], t);
            t = fmaf(xr1, ew1[1*50+j], t);
            t = fmaf(xr2, ew1[2*50+j], t);
            t = fmaf(xc0, ew1[3*50+j], t);
            t = fmaf(xc1, ew1[4*50+j], t);
            t = fmaf(xc2, ew1[5*50+j], t);
            t = fmaf(a0,  ew1[6*50+j], t);
            t = fmaf(a1,  ew1[7*50+j], t);
            t = fmaf(a2,  ew1[8*50+j], t);
            h[j] = fmaxf(t, 0.f);
        }

        // edge MLP layer 2: 50 -> 15
        float e2[15];
#pragma unroll
        for (int j = 0; j < 15; ++j) e2[j] = eb2[j];
#pragma unroll
        for (int i2 = 0; i2 < 50; ++i2) {
            float v = h[i2];
#pragma unroll
            for (int j = 0; j < 15; ++j) e2[j] = fmaf(v, ew2[i2*15+j], e2[j]);
        }

        // node MLP layer 1: [x[col](3), e2(15)] -> 50, ReLU, accumulate
#pragma unroll
        for (int j = 0; j < 50; ++j) {
            float t = nb1[j];
            t = fmaf(xc0, nw1[0*50+j], t);
            t = fmaf(xc1, nw1[1*50+j], t);
            t = fmaf(xc2, nw1[2*50+j], t);
#pragma unroll
            for (int i2 = 0; i2 < 15; ++i2)
                t = fmaf(e2[i2], nw1[(3+i2)*50+j], t);
            hacc[j] += fmaxf(t, 0.f);
        }
    }

    // butterfly reduce hacc across the 8 lanes (all lanes end with the sum)
#pragma unroll
    for (int m = 4; m > 0; m >>= 1) {
#pragma unroll
        for (int j = 0; j < 50; ++j)
            hacc[j] += __shfl_xor(hacc[j], m, GRP);
    }

    float deg = (float)(s1 - s0);
    float inv = 1.f / fmaxf(deg, 1.f);
    int g = batch[n];
    float* dst = g_acc + (size_t)g * 16;

    // node MLP layer 2 once per node; lane l emits features 2l, 2l+1
    int j0 = 2 * lane;
#pragma unroll
    for (int j = 0; j < 2; ++j) {
        int jj = j0 + j;
        if (jj < 15) {
            float acc = deg * nb2[jj];
#pragma unroll
            for (int i2 = 0; i2 < 50; ++i2)
                acc = fmaf(hacc[i2], nw2[i2*15+jj], acc);
            atomicAdd(dst + jj, acc * inv);
        }
    }
    if (lane == GRP - 1) atomicAdd(dst + 15, 1.f);
}

// ---------------------------------------------------------------------------
// Global MLP + head (fc1 -> BN(batch stats) -> ReLU -> fc2 -> log_softmax)
// ---------------------------------------------------------------------------
__global__ __launch_bounds__(256) void global_head_kernel(
    const float* __restrict__ g_acc, const float* __restrict__ u,
    const float* __restrict__ gw1, const float* __restrict__ gb1,
    const float* __restrict__ gw2, const float* __restrict__ gb2,
    const float* __restrict__ f1w, const float* __restrict__ f1b,
    const float* __restrict__ bng, const float* __restrict__ bnb,
    const float* __restrict__ f2w, const float* __restrict__ f2b,
    float* __restrict__ out, int G)
{
    __shared__ float z[1024 * 10];   // 40 KB, G <= 1024
    __shared__ float red[2][10];

    float psum[10], psq[10];
#pragma unroll
    for (int j = 0; j < 10; ++j) { psum[j] = 0.f; psq[j] = 0.f; }

    for (int g = threadIdx.x; g < G; g += 256) {
        float gin[16];
        gin[0] = u[g];
        const float* src = g_acc + (size_t)g * 16;
        float inv = 1.f / fmaxf(src[15], 1.f);
#pragma unroll
        for (int j = 0; j < 15; ++j) gin[1 + j] = src[j] * inv;

        float h[50];
#pragma unroll
        for (int j = 0; j < 50; ++j) h[j] = gb1[j];
#pragma unroll
        for (int i = 0; i < 16; ++i) {
            float v = gin[i];
#pragma unroll
            for (int j = 0; j < 50; ++j) h[j] = fmaf(v, gw1[i*50+j], h[j]);
        }
#pragma unroll
        for (int j = 0; j < 50; ++j) h[j] = fmaxf(h[j], 0.f);

        float u2[15];
#pragma unroll
        for (int j = 0; j < 15; ++j) u2[j] = gb2[j];
#pragma unroll
        for (int i = 0; i < 50; ++i) {
            float v = h[i];
#pragma unroll
            for (int j = 0; j < 15; ++j) u2[j] = fmaf(v, gw2[i*15+j], u2[j]);
        }

#pragma unroll
        for (int j = 0; j < 10; ++j) {
            float acc = f1b[j];
#pragma unroll
            for (int i = 0; i < 15; ++i) acc = fmaf(u2[i], f1w[i*10+j], acc);
            z[g*10 + j] = acc;
            psum[j] += acc;
            psq[j]  += acc * acc;
        }
    }

    if (threadIdx.x == 0) {
#pragma unroll
        for (int j = 0; j < 10; ++j) { red[0][j] = 0.f; red[1][j] = 0.f; }
    }
    __syncthreads();
#pragma unroll
    for (int j = 0; j < 10; ++j) {
        atomicAdd(&red[0][j], psum[j]);
        atomicAdd(&red[1][j], psq[j]);
    }
    __syncthreads();

    float mean[10], rstd[10];
    float invG = 1.f / (float)G;
#pragma unroll
    for (int j = 0; j < 10; ++j) {
        mean[j] = red[0][j] * invG;
        float var = red[1][j] * invG - mean[j] * mean[j];
        rstd[j] = rsqrtf(var + 1e-5f);
    }

    for (int g = threadIdx.x; g < G; g += 256) {
        float l[6];
#pragma unroll
        for (int k = 0; k < 6; ++k) l[k] = f2b[k];
#pragma unroll
        for (int j = 0; j < 10; ++j) {
            float zn = (z[g*10 + j] - mean[j]) * rstd[j] * bng[j] + bnb[j];
            zn = fmaxf(zn, 0.f);
#pragma unroll
            for (int k = 0; k < 6; ++k) l[k] = fmaf(zn, f2w[j*6+k], l[k]);
        }
        float m = l[0];
#pragma unroll
        for (int k = 1; k < 6; ++k) m = fmaxf(m, l[k]);
        float s = 0.f;
#pragma unroll
        for (int k = 0; k < 6; ++k) s += expf(l[k] - m);
        float lse = m + logf(s);
#pragma unroll
        for (int k = 0; k < 6; ++k) out[g*6 + k] = l[k] - lse;
    }
}

extern "C" void kernel_launch(void* const* d_in, const int* in_sizes, int n_in,
                              void* d_out, int out_size, void* d_ws, size_t ws_size,
                              hipStream_t stream)
{
    const float* x   = (const float*)d_in[0];
    const int*   ei  = (const int*)d_in[1];
    const float* ea  = (const float*)d_in[2];
    const float* u   = (const float*)d_in[3];
    const int* batch = (const int*)d_in[4];
    const float* ew1 = (const float*)d_in[5];
    const float* eb1 = (const float*)d_in[6];
    const float* ew2 = (const float*)d_in[7];
    const float* eb2 = (const float*)d_in[8];
    const float* nw1 = (const float*)d_in[9];
    const float* nb1 = (const float*)d_in[10];
    const float* nw2 = (const float*)d_in[11];
    const float* nb2 = (const float*)d_in[12];
    const float* gw1 = (const float*)d_in[13];
    const float* gb1 = (const float*)d_in[14];
    const float* gw2 = (const float*)d_in[15];
    const float* gb2 = (const float*)d_in[16];
    const float* f1w = (const float*)d_in[17];
    const float* f1b = (const float*)d_in[18];
    const float* bng = (const float*)d_in[19];
    const float* bnb = (const float*)d_in[20];
    const float* f2w = (const float*)d_in[21];
    const float* f2b = (const float*)d_in[22];

    int N = in_sizes[0] / 3;
    int E = in_sizes[1] / 2;
    int G = in_sizes[3];

    // workspace layout (all 4-byte aligned)
    unsigned* cnt  = (unsigned*)d_ws;            // N
    unsigned* off  = cnt + N;                    // N+1
    unsigned* cur  = off + (N + 1);              // N
    unsigned* perm = cur + N;                    // E
    float*    g_acc = (float*)(perm + E);        // G*16
    // total: (3N+1+E)*4 + G*64  ~= 14 MB

    hipMemsetAsync(cnt, 0, sizeof(unsigned) * (size_t)N, stream);
    hipMemsetAsync(g_acc, 0, sizeof(float) * (size_t)G * 16, stream);

    hist_kernel<<<(E + TPB - 1) / TPB, TPB, 0, stream>>>(ei, cnt, E);
    scan_kernel<<<1, 1024, 0, stream>>>(cnt, off, cur, N, E);
    scatter_kernel<<<(E + TPB - 1) / TPB, TPB, 0, stream>>>(ei, cur, perm, E);

    node_kernel<<<(N + (TPB/GRP) - 1) / (TPB/GRP), TPB, 0, stream>>>(
        x, ei, ea, off, perm, batch,
        ew1, eb1, ew2, eb2, nw1, nb1, nw2, nb2, g_acc, N, E);

    global_head_kernel<<<1, 256, 0, stream>>>(
        g_acc, u, gw1, gb1, gw2, gb2, f1w, f1b, bng, bnb, f2w, f2b,
        (float*)d_out, G);
}